// Round 8
// baseline (244.480 us; speedup 1.0000x reference)
//
#include <hip/hip_runtime.h>
#include <hip/hip_bf16.h>
#include <stdint.h>
#include <math.h>

// ---------- types ----------
typedef __bf16 bf16x8 __attribute__((ext_vector_type(8)));
typedef float  f32x4  __attribute__((ext_vector_type(4)));
typedef unsigned int u32x4 __attribute__((ext_vector_type(4)));

__device__ __forceinline__ unsigned short f2bf(float x) {
    union { float f; unsigned u; } v; v.f = x;
    unsigned r = v.u + 0x7fffu + ((v.u >> 16) & 1u);   // RNE
    return (unsigned short)(r >> 16);
}

__device__ __forceinline__ float bf2f(unsigned short b) {
    union { unsigned u; float f; } v; v.u = ((unsigned)b) << 16; return v.f;
}

__device__ __forceinline__ void async16(const void* g, void* l) {
    __builtin_amdgcn_global_load_lds(
        (const __attribute__((address_space(1))) void*)g,
        (__attribute__((address_space(3))) void*)l,
        16, 0, 0);
}

// ---------- bf16 B^T GEMM, 128x256 tile, BK=32, 4 waves (64x128 each) ----------
// Wider tile amortizes the ~600cyc/step fixed sync overhead over 2x MFMA
// (32 MFMA/wave/step) and cuts ds_read:MFMA from 0.5 to 0.375.
// TRIPLE-BUFFERED with counted vmcnt: stage t+2 each iter, wait vmcnt(6).
// LDS: 3 bufs x [A 128x32 | B 256x32] = 72 KB -> 2 blocks/CU.
//
// A: M x K (row-major bf16, lda), Bt: N x K (row-major, ldb)
// C[m][n] = scale * sum_k A[m][k] * Bt[n][k]
// VFOLD: n0 >= nsplit -> tile stored TRANSPOSED to VtOut.
// KLIMIT: Keff = (bm+1)*128 (causal clamp).
// ZMODE (z-pure XCD swizzle; gridDim.x%8==0 => XCD = blockIdx.x&7; bz=xcd>>1;
// blockIdx.z is part of the TILE index, not the batch):
//   1 QKV: gx=192,gz=4; tile=(x&1)*96+q*4+z -> bn=tile/16 (12), bm=tile%16
//   2 S:   gx=72, gz=4; t=(x&1)*36+q*4+z -> causal 256-wide triangle (72/z)
//   3 PV:  gx=64, gz=4; tile=(x&1)*32+q*4+z -> bn=tile>>4 (4), bm=15-(tile&15)
template <typename OutT, bool KLIMIT, bool VFOLD, int ZMODE>
__global__ __launch_bounds__(256, 2) void gemm_bt(
    const unsigned short* __restrict__ A,
    const unsigned short* __restrict__ Bt,
    OutT* __restrict__ C,
    unsigned short* __restrict__ VtOut,
    int M, int N, int K, int lda, int ldb, int ldc,
    int ldvt, int nsplit,
    long long sA, long long sB, long long sC, long long sVt, float scale)
{
    int bn, bm, bz;
    if constexpr (ZMODE == 1) {            // QKV: 12 bn x 16 bm per z
        const int o = blockIdx.x, x = o & 7, q = o >> 3;
        bz = x >> 1;
        const int tile = (x & 1) * 96 + q * 4 + blockIdx.z;
        bn = tile / 16; bm = tile % 16;
    } else if constexpr (ZMODE == 2) {     // S: 256-wide causal triangle (72/z)
        const int o = blockIdx.x, x = o & 7, q = o >> 3;
        bz = x >> 1;
        const int t = (x & 1) * 36 + q * 4 + blockIdx.z;
        int acc2 = 0; bm = 0;
        while (acc2 + (bm / 2 + 1) <= t) { acc2 += bm / 2 + 1; bm++; }
        bn = t - acc2;                     // bn <= bm/2
    } else if constexpr (ZMODE == 3) {     // PV: 4 bn x 16 bm per z, heavy-first
        const int o = blockIdx.x, x = o & 7, q = o >> 3;
        bz = x >> 1;
        const int tile = (x & 1) * 32 + q * 4 + blockIdx.z;
        bn = tile >> 4; bm = 15 - (tile & 15);
    } else {
        bn = blockIdx.x; bm = blockIdx.y; bz = blockIdx.z;
    }

    A  += (long long)bz * sA;
    Bt += (long long)bz * sB;
    C  += (long long)bz * sC;

    const int m0 = bm * 128, n0 = bn * 256;
    const int Keff = KLIMIT ? min(K, (bm + 1) * 128) : K;
    const int nsteps = Keff >> 5;

    // 3 bufs x [A:128x32 (8KB) | B:256x32 (16KB)] = 72 KB
    __shared__ __align__(16) unsigned short LDS[3 * 12288];

    const int tid  = threadIdx.x;
    const int w    = tid >> 6, l = tid & 63;
    const int wr   = w >> 1,  wc = w & 1;     // wave tile: rows 64*wr, cols 128*wc
    const int lrow = l & 15,  quad = l >> 4;

    f32x4 acc[4][8] = {};

    // staging: physical k-slot l&3 holds logical chunk (l&3)^((l>>3)&3)
    const int cOff = (((l & 3) ^ ((l >> 3) & 3))) * 8;
    // A: wave w stages rows [32w, 32w+32)
    const unsigned short* aG0 = A  + (long long)(m0 + 32 * w + (l >> 2))      * lda + cOff;
    const unsigned short* aG1 = A  + (long long)(m0 + 32 * w + (l >> 2) + 16) * lda + cOff;
    // B: wave w stages rows [64w, 64w+64)
    const unsigned short* bG0 = Bt + (long long)(n0 + 64 * w + (l >> 2))      * ldb + cOff;
    const unsigned short* bG1 = Bt + (long long)(n0 + 64 * w + (l >> 2) + 16) * ldb + cOff;
    const unsigned short* bG2 = Bt + (long long)(n0 + 64 * w + (l >> 2) + 32) * ldb + cOff;
    const unsigned short* bG3 = Bt + (long long)(n0 + 64 * w + (l >> 2) + 48) * ldb + cOff;
    unsigned short* aL = &LDS[w * 1024 + l * 8];          // A region of buf0
    unsigned short* bL = &LDS[4096 + w * 2048 + l * 8];   // B region of buf0

    const int sl = (lrow >> 1) & 3;   // un-swizzle for fragment reads

    // stage K-tile s into buf s%3 (6 x 16B loads per thread)
    auto STG = [&](int s) {
        const int off = (s % 3) * 12288;
        const int kk  = s * 32;
        async16(aG0 + kk, aL + off);
        async16(aG1 + kk, aL + off + 512);
        async16(bG0 + kk, bL + off);
        async16(bG1 + kk, bL + off + 512);
        async16(bG2 + kk, bL + off + 1024);
        async16(bG3 + kk, bL + off + 1536);
    };

    STG(0);
    if (nsteps > 1) STG(1);

    for (int t = 0; t < nsteps; ++t) {
        // wait for stage t only (stage t+1's 6 loads stay in flight)
        if (t + 1 < nsteps) asm volatile("s_waitcnt vmcnt(6)" ::: "memory");
        else                asm volatile("s_waitcnt vmcnt(0)" ::: "memory");
        __builtin_amdgcn_s_barrier();
        asm volatile("" ::: "memory");            // no LDS-read hoist above barrier

        if (t + 2 < nsteps) STG(t + 2);           // overwrites buf last read at t-1

        const unsigned short* As = &LDS[(t % 3) * 12288];
        const unsigned short* Bs = As + 4096;
        bf16x8 af[4], bfr[8];
#pragma unroll
        for (int i = 0; i < 4; i++)
            af[i]  = *(const bf16x8*)&As[(wr * 64 + i * 16 + lrow) * 32 + (quad ^ sl) * 8];
#pragma unroll
        for (int j = 0; j < 8; j++)
            bfr[j] = *(const bf16x8*)&Bs[(wc * 128 + j * 16 + lrow) * 32 + (quad ^ sl) * 8];
#pragma unroll
        for (int i = 0; i < 4; i++)
#pragma unroll
            for (int j = 0; j < 8; j++)
                acc[i][j] = __builtin_amdgcn_mfma_f32_16x16x32_bf16(af[i], bfr[j], acc[i][j], 0, 0, 0);
    }

    // ---- VFOLD: store this tile transposed, straight from acc ----
    if constexpr (VFOLD) {
        if (n0 >= nsplit) {
            unsigned short* Vp = VtOut + (long long)bz * sVt;
#pragma unroll
            for (int i = 0; i < 4; i++) {
                const int t = m0 + wr * 64 + i * 16 + quad * 4;
#pragma unroll
                for (int j = 0; j < 8; j++) {
                    const int d = (n0 - nsplit) + wc * 128 + j * 16 + lrow;
                    union { unsigned short u[4]; uint2 p; } o;
#pragma unroll
                    for (int r = 0; r < 4; r++) o.u[r] = f2bf(acc[i][j][r] * scale);
                    *(uint2*)(Vp + (long long)d * ldvt + t) = o.p;
                }
            }
            return;
        }
    }

    __syncthreads();   // all waves done before LDS is reused for repack

    // ---- epilogue: per-wave LDS repack ----
    const int erow = l >> 2, ep = l & 3;

    if constexpr (sizeof(OutT) == 2) {
        // 16 rows x 256B (+16 pad) per wave
        char* eb = (char*)LDS + w * 4352;
#pragma unroll
        for (int i = 0; i < 4; i++) {
#pragma unroll
            for (int j = 0; j < 8; j++)
#pragma unroll
                for (int r = 0; r < 4; r++)
                    *(unsigned short*)(eb + (quad * 4 + r) * 272 + (j * 16 + lrow) * 2) =
                        f2bf(acc[i][j][r] * scale);
            const long long gm = m0 + wr * 64 + i * 16 + erow;
#pragma unroll
            for (int c = 0; c < 4; c++) {
                u32x4 d = *(u32x4*)(eb + erow * 272 + ep * 64 + c * 16);
                *(u32x4*)((unsigned short*)C + gm * ldc + (n0 + wc * 128 + ep * 32 + c * 8)) = d;
            }
        }
    } else {
        // 16 rows x 128B (+16 pad) per wave, 4 col-chunks of 32
        char* eb = (char*)LDS + w * 2304;
#pragma unroll
        for (int i = 0; i < 4; i++) {
            const long long gm = m0 + wr * 64 + i * 16 + erow;
#pragma unroll
            for (int jc = 0; jc < 4; jc++) {
#pragma unroll
                for (int jj = 0; jj < 2; jj++)
#pragma unroll
                    for (int r = 0; r < 4; r++)
                        *(float*)(eb + (quad * 4 + r) * 144 + (jj * 16 + lrow) * 4) =
                            acc[i][2 * jc + jj][r] * scale;
#pragma unroll
                for (int c = 0; c < 2; c++) {
                    f32x4 d = *(f32x4*)(eb + erow * 144 + ep * 32 + c * 16);
                    *(f32x4*)((float*)C + gm * ldc + (n0 + wc * 128 + jc * 32 + ep * 8 + c * 4)) = d;
                }
            }
        }
    }
}

// ---------- fused prep: x fp32->bf16 cast  +  W_{q,k,v} transpose-cast ----------
__global__ __launch_bounds__(256) void prep_fused(
    const float4* __restrict__ xin, unsigned short* __restrict__ xout, int n4, int nCast,
    const float* __restrict__ W0, const float* __restrict__ W1,
    const float* __restrict__ W2, unsigned short* __restrict__ wout, int n)
{
    const int tid = threadIdx.x;
    if ((int)blockIdx.x < nCast) {
        int i = blockIdx.x * 256 + tid;
        if (i >= n4) return;
        float4 v = xin[i];
        union { unsigned short u[4]; uint2 p; } o;
        o.u[0] = f2bf(v.x); o.u[1] = f2bf(v.y); o.u[2] = f2bf(v.z); o.u[3] = f2bf(v.w);
        *(uint2*)(xout + (long long)i * 4) = o.p;
        return;
    }
    const int bx = blockIdx.x - nCast;       // 0..3071
    const int wz = bx >> 10, rem = bx & 1023;
    const int wy = rem >> 5, wx = rem & 31;
    const float* in = (wz == 0) ? W0 : (wz == 1) ? W1 : W2;
    unsigned short* out = wout + (long long)wz * n * n;
    __shared__ float tile[32][33];
    const int tx = tid & 31, ty = tid >> 5;
    const int c0 = wx * 32, r0 = wy * 32;
#pragma unroll
    for (int i = 0; i < 4; i++)
        tile[ty + i * 8][tx] = in[(long long)(r0 + ty + i * 8) * n + c0 + tx];
    __syncthreads();
#pragma unroll
    for (int i = 0; i < 4; i++)
        out[(long long)(c0 + ty + i * 8) * n + r0 + tx] = f2bf(tile[tx][ty + i * 8]);
}

// ---------- causal softmax: S (bf16, B*T rows of T) -> P (bf16), vectorized ----------
__global__ __launch_bounds__(256) void causal_softmax_bf16(
    const unsigned short* __restrict__ S, unsigned short* __restrict__ P, int T)
{
    const int row = blockIdx.x;            // 0 .. B*T-1
    const int t   = row & (T - 1);
    const int L   = t + 1;
    const unsigned short* s = S + (long long)row * T;
    unsigned short* p = P + (long long)row * T;
    const int tid  = threadIdx.x;
    const int base = tid * 8;

    uint4 raw = *(const uint4*)(s + base);
    unsigned rr[4] = {raw.x, raw.y, raw.z, raw.w};
    float v[8];
#pragma unroll
    for (int k = 0; k < 4; k++) {
        union { unsigned u; float f; } a, b;
        a.u = (rr[k] & 0xFFFFu) << 16;
        b.u = rr[k] & 0xFFFF0000u;
        v[2 * k] = a.f; v[2 * k + 1] = b.f;
    }
    float mx = -3.0e38f;
#pragma unroll
    for (int k = 0; k < 8; k++) {
        if (base + k >= L) v[k] = -3.0e38f;
        mx = fmaxf(mx, v[k]);
    }
#pragma unroll
    for (int off = 32; off; off >>= 1) mx = fmaxf(mx, __shfl_xor(mx, off));
    __shared__ float red[4], red2[4];
    const int wid = tid >> 6, lid = tid & 63;
    if (lid == 0) red[wid] = mx;
    __syncthreads();
    mx = fmaxf(fmaxf(red[0], red[1]), fmaxf(red[2], red[3]));

    float sum = 0.f;
#pragma unroll
    for (int k = 0; k < 8; k++) { v[k] = __expf(v[k] - mx); sum += v[k]; }
#pragma unroll
    for (int off = 32; off; off >>= 1) sum += __shfl_xor(sum, off);
    if (lid == 0) red2[wid] = sum;
    __syncthreads();
    sum = red2[0] + red2[1] + red2[2] + red2[3];
    const float inv = 1.0f / sum;

    union { unsigned short u[8]; uint4 q; } o;
#pragma unroll
    for (int k = 0; k < 8; k++) o.u[k] = f2bf(v[k] * inv);
    *(uint4*)(p + base) = o.q;
}

// ---------- launch ----------
extern "C" void kernel_launch(void* const* d_in, const int* in_sizes, int n_in,
                              void* d_out, int out_size, void* d_ws, size_t ws_size,
                              hipStream_t stream)
{
    const int B = 4, T = 2048, C = 1024, D = 1024;
    const float* x  = (const float*)d_in[0];
    const float* Wq = (const float*)d_in[1];
    const float* Wk = (const float*)d_in[2];
    const float* Wv = (const float*)d_in[3];
    float* out = (float*)d_out;
    char* ws = (char*)d_ws;

    const size_t MB = 1ull << 20;
    unsigned short* Xbf   = (unsigned short*)(ws + 0);
    unsigned short* WqkvT = (unsigned short*)(ws + 16 * MB);
    unsigned short* QK    = (unsigned short*)(ws + 22 * MB);
    unsigned short* Vt    = (unsigned short*)(ws + 54 * MB);
    unsigned short* Sbf   = (unsigned short*)(ws + 70 * MB);
    unsigned short* P     = (unsigned short*)(ws + 0);

    const long long sX  = (long long)T * C;        // 2048*1024
    const long long sQK = (long long)T * 2 * D;    // 2048*2048
    const long long sVt = (long long)D * T;        // 1024*2048
    const long long sS  = (long long)T * T;        // 2048*2048
    const long long sO  = (long long)T * D;        // 2048*1024

    // 1) fused prep: x -> bf16 cast  +  W^T cast (one launch)
    {
        int n4 = B * T * C / 4;                    // 2,097,152
        int nCast = (n4 + 255) / 256;              // 8192
        prep_fused<<<dim3(nCast + 3072), dim3(256), 0, stream>>>(
            (const float4*)x, Xbf, n4, nCast, Wq, Wk, Wv, WqkvT, 1024);
    }
    // 2) fused QKV GEMM (128x256 tile): Q,K -> QK; V -> Vt transposed (VFOLD)
    {
        dim3 g(192, 1, 4), b(256);
        gemm_bt<unsigned short, false, true, 1><<<g, b, 0, stream>>>(
            Xbf, WqkvT, QK, Vt, 2048, 3072, 1024, 1024, 1024, 2048,
            /*ldvt*/ T, /*nsplit*/ 2048, sX, 0, sQK, sVt, 1.0f);
    }
    // 3) S = Q K^T / 32 -> bf16, 256-wide causal triangle, z-pure XCD
    {
        dim3 g(72, 1, 4), b(256);
        gemm_bt<unsigned short, false, false, 2><<<g, b, 0, stream>>>(
            QK, QK + D, Sbf, nullptr, 2048, 2048, 1024, 2 * D, 2 * D, 2048,
            0, 0, sQK, sQK, sS, 0, 0.03125f);
    }
    // 4) causal softmax (bf16 -> bf16)
    {
        causal_softmax_bf16<<<dim3(B * T), dim3(256), 0, stream>>>(Sbf, P, T);
    }
    // 5) O = P V (K clamped causally, heavy-first within XCD), z-pure XCD
    {
        dim3 g(64, 1, 4), b(256);
        gemm_bt<float, true, false, 3><<<g, b, 0, stream>>>(
            P, Vt, out, nullptr, 2048, 1024, 2048, 2048, 2048, 1024,
            0, 0, sS, sVt, sO, 0, 1.0f);
    }
    (void)in_sizes; (void)n_in; (void)out_size; (void)ws_size;
}

// Round 9
// 235.490 us; speedup vs baseline: 1.0382x; 1.0382x over previous
//
#include <hip/hip_runtime.h>
#include <hip/hip_bf16.h>
#include <stdint.h>
#include <math.h>

// ---------- types ----------
typedef __bf16 bf16x8 __attribute__((ext_vector_type(8)));
typedef float  f32x4  __attribute__((ext_vector_type(4)));
typedef unsigned int u32x4 __attribute__((ext_vector_type(4)));

__device__ __forceinline__ unsigned short f2bf(float x) {
    union { float f; unsigned u; } v; v.f = x;
    unsigned r = v.u + 0x7fffu + ((v.u >> 16) & 1u);   // RNE
    return (unsigned short)(r >> 16);
}

__device__ __forceinline__ float bf2f(unsigned short b) {
    union { unsigned u; float f; } v; v.u = ((unsigned)b) << 16; return v.f;
}

__device__ __forceinline__ void async16(const void* g, void* l) {
    __builtin_amdgcn_global_load_lds(
        (const __attribute__((address_space(1))) void*)g,
        (__attribute__((address_space(3))) void*)l,
        16, 0, 0);
}

// ---------- bf16 B^T GEMM, 128xTN tile (TN=128 or 256), BK=32, 4 waves ----------
// TRIPLE-BUFFERED with counted vmcnt: stage t+2 each iter, wait for stage t
// only (stage t+1's loads stay in flight across the barrier).
// TN=256 (QKV, 768 blocks): amortizes the per-step sync overhead over 2x MFMA.
//   LDS 72KB -> 2 blocks/CU. Proven 69.6us r8.
// TN=128 (S/PV, 544/512 blocks): keeps >=2 blocks/CU stall-sharing (r8 showed
//   TN=256 at ~1 block/CU regresses 2x). LDS 48KB -> 3 blocks/CU. Proven r7.
//
// A: M x K (row-major bf16, lda), Bt: N x K (row-major, ldb)
// C[m][n] = scale * sum_k A[m][k] * Bt[n][k]
// VFOLD: n0 >= nsplit -> tile stored TRANSPOSED to VtOut.
// KLIMIT: Keff = (bm+1)*128 (causal clamp).
// ZMODE (z-pure XCD swizzle; gridDim.x%8==0 => XCD = blockIdx.x&7; bz=xcd>>1;
// blockIdx.z is part of the TILE index, not the batch):
//   1 QKV TN=256: gx=192,gz=4; tile=(x&1)*96+q*4+z -> bn=tile/16, bm=tile%16
//   2 S   TN=128: gx=136,gz=4; t=(x&1)*68+q*4+z -> triangular (bm,bn), bn<=bm
//   3 PV  TN=128: gx=128,gz=4; tile=(x&1)*64+q*4+z -> bn=tile>>4, bm=15-(tile&15)
template <typename OutT, bool KLIMIT, bool VFOLD, int ZMODE, int TN>
__global__ __launch_bounds__(256, (TN == 128) ? 3 : 2) void gemm_bt(
    const unsigned short* __restrict__ A,
    const unsigned short* __restrict__ Bt,
    OutT* __restrict__ C,
    unsigned short* __restrict__ VtOut,
    int M, int N, int K, int lda, int ldb, int ldc,
    int ldvt, int nsplit,
    long long sA, long long sB, long long sC, long long sVt, float scale)
{
    constexpr int NJ   = TN / 32;                 // B fragments per wave
    constexpr int BUFE = (TN == 128) ? 8192 : 12288;   // shorts per buffer

    int bn, bm, bz;
    if constexpr (ZMODE == 1) {            // QKV: 12 bn x 16 bm per z
        const int o = blockIdx.x, x = o & 7, q = o >> 3;
        bz = x >> 1;
        const int tile = (x & 1) * 96 + q * 4 + blockIdx.z;
        bn = tile / 16; bm = tile % 16;
    } else if constexpr (ZMODE == 2) {     // S: packed causal triangle (136/z)
        const int o = blockIdx.x, x = o & 7, q = o >> 3;
        bz = x >> 1;
        const int t = (x & 1) * 68 + q * 4 + blockIdx.z;
        int r = (int)((sqrtf(8.f * (float)t + 1.f) - 1.f) * 0.5f);
        while ((r + 1) * (r + 2) / 2 <= t) r++;
        while (r * (r + 1) / 2 > t) r--;
        bm = r; bn = t - r * (r + 1) / 2;  // bn <= bm
    } else if constexpr (ZMODE == 3) {     // PV: 8 bn x 16 bm per z, heavy-first
        const int o = blockIdx.x, x = o & 7, q = o >> 3;
        bz = x >> 1;
        const int tile = (x & 1) * 64 + q * 4 + blockIdx.z;
        bn = tile >> 4; bm = 15 - (tile & 15);
    } else {
        bn = blockIdx.x; bm = blockIdx.y; bz = blockIdx.z;
    }

    A  += (long long)bz * sA;
    Bt += (long long)bz * sB;
    C  += (long long)bz * sC;

    const int m0 = bm * 128, n0 = bn * TN;
    const int Keff = KLIMIT ? min(K, (bm + 1) * 128) : K;
    const int nsteps = Keff >> 5;

    __shared__ __align__(16) unsigned short LDS[3 * BUFE];

    const int tid  = threadIdx.x;
    const int w    = tid >> 6, l = tid & 63;
    const int wr   = w >> 1,  wc = w & 1;     // wave tile: rows 64*wr, cols (TN/2)*wc
    const int lrow = l & 15,  quad = l >> 4;

    f32x4 acc[4][NJ] = {};

    // staging: physical k-slot l&3 holds logical chunk (l&3)^((l>>3)&3)
    const int cOff = (((l & 3) ^ ((l >> 3) & 3))) * 8;
    // A: wave w stages rows [32w, 32w+32)
    const unsigned short* aG0 = A + (long long)(m0 + 32 * w + (l >> 2))      * lda + cOff;
    const unsigned short* aG1 = A + (long long)(m0 + 32 * w + (l >> 2) + 16) * lda + cOff;
    // B: wave w stages rows [  (TN/4)*w, (TN/4)*(w+1) )
    const unsigned short* bG0 = Bt + (long long)(n0 + (TN / 4) * w + (l >> 2))      * ldb + cOff;
    const unsigned short* bG1 = Bt + (long long)(n0 + (TN / 4) * w + (l >> 2) + 16) * ldb + cOff;
    const unsigned short* bG2 = Bt + (long long)(n0 + (TN / 4) * w + (l >> 2) + 32) * ldb + cOff;
    const unsigned short* bG3 = Bt + (long long)(n0 + (TN / 4) * w + (l >> 2) + 48) * ldb + cOff;
    unsigned short* aL = &LDS[w * 1024 + l * 8];                       // A region of buf0
    unsigned short* bL = &LDS[4096 + w * (TN * 8) + l * 8];            // B region of buf0

    const int sl = (lrow >> 1) & 3;   // un-swizzle for fragment reads

    // stage K-tile s into buf s%3
    auto STG = [&](int s) {
        const int off = (s % 3) * BUFE;
        const int kk  = s * 32;
        async16(aG0 + kk, aL + off);
        async16(aG1 + kk, aL + off + 512);
        async16(bG0 + kk, bL + off);
        async16(bG1 + kk, bL + off + 512);
        if constexpr (TN == 256) {
            async16(bG2 + kk, bL + off + 1024);
            async16(bG3 + kk, bL + off + 1536);
        }
    };

    STG(0);
    if (nsteps > 1) STG(1);

    for (int t = 0; t < nsteps; ++t) {
        // wait for stage t only (stage t+1's loads stay in flight)
        if (t + 1 < nsteps) {
            if constexpr (TN == 128) asm volatile("s_waitcnt vmcnt(4)" ::: "memory");
            else                     asm volatile("s_waitcnt vmcnt(6)" ::: "memory");
        } else {
            asm volatile("s_waitcnt vmcnt(0)" ::: "memory");
        }
        __builtin_amdgcn_s_barrier();
        asm volatile("" ::: "memory");            // no LDS-read hoist above barrier

        if (t + 2 < nsteps) STG(t + 2);           // overwrites buf last read at t-1

        const unsigned short* As = &LDS[(t % 3) * BUFE];
        const unsigned short* Bs = As + 4096;
        bf16x8 af[4], bfr[NJ];
#pragma unroll
        for (int i = 0; i < 4; i++)
            af[i]  = *(const bf16x8*)&As[(wr * 64 + i * 16 + lrow) * 32 + (quad ^ sl) * 8];
#pragma unroll
        for (int j = 0; j < NJ; j++)
            bfr[j] = *(const bf16x8*)&Bs[(wc * (TN / 2) + j * 16 + lrow) * 32 + (quad ^ sl) * 8];
#pragma unroll
        for (int i = 0; i < 4; i++)
#pragma unroll
            for (int j = 0; j < NJ; j++)
                acc[i][j] = __builtin_amdgcn_mfma_f32_16x16x32_bf16(af[i], bfr[j], acc[i][j], 0, 0, 0);
    }

    // ---- VFOLD: store this tile transposed, straight from acc ----
    if constexpr (VFOLD) {
        if (n0 >= nsplit) {
            unsigned short* Vp = VtOut + (long long)bz * sVt;
#pragma unroll
            for (int i = 0; i < 4; i++) {
                const int t = m0 + wr * 64 + i * 16 + quad * 4;
#pragma unroll
                for (int j = 0; j < NJ; j++) {
                    const int d = (n0 - nsplit) + wc * (TN / 2) + j * 16 + lrow;
                    union { unsigned short u[4]; uint2 p; } o;
#pragma unroll
                    for (int r = 0; r < 4; r++) o.u[r] = f2bf(acc[i][j][r] * scale);
                    *(uint2*)(Vp + (long long)d * ldvt + t) = o.p;
                }
            }
            return;
        }
    }

    __syncthreads();   // all waves done before LDS is reused for repack

    // ---- epilogue: per-wave LDS repack ----
    const int erow = l >> 2, ep = l & 3;

    if constexpr (sizeof(OutT) == 2 && TN == 128) {
        char* eb = (char*)LDS + w * 2288;          // 16 rows x 144B
#pragma unroll
        for (int i = 0; i < 4; i++) {
#pragma unroll
            for (int j = 0; j < 4; j++)
#pragma unroll
                for (int r = 0; r < 4; r++)
                    *(unsigned short*)(eb + (quad * 4 + r) * 144 + (j * 16 + lrow) * 2) =
                        f2bf(acc[i][j][r] * scale);
            const long long gm = m0 + wr * 64 + i * 16 + erow;
#pragma unroll
            for (int c = 0; c < 2; c++) {
                u32x4 d = *(u32x4*)(eb + erow * 144 + ep * 32 + c * 16);
                *(u32x4*)((unsigned short*)C + gm * ldc + (n0 + wc * 64 + ep * 16 + c * 8)) = d;
            }
        }
    } else if constexpr (sizeof(OutT) == 2 && TN == 256) {
        char* eb = (char*)LDS + w * 4352;          // 16 rows x 272B
#pragma unroll
        for (int i = 0; i < 4; i++) {
#pragma unroll
            for (int j = 0; j < 8; j++)
#pragma unroll
                for (int r = 0; r < 4; r++)
                    *(unsigned short*)(eb + (quad * 4 + r) * 272 + (j * 16 + lrow) * 2) =
                        f2bf(acc[i][j][r] * scale);
            const long long gm = m0 + wr * 64 + i * 16 + erow;
#pragma unroll
            for (int c = 0; c < 4; c++) {
                u32x4 d = *(u32x4*)(eb + erow * 272 + ep * 64 + c * 16);
                *(u32x4*)((unsigned short*)C + gm * ldc + (n0 + wc * 128 + ep * 32 + c * 8)) = d;
            }
        }
    } else {
        // fp32 out (PV, TN=128): 16 rows x 144B per wave, 2 col-chunks of 32
        char* eb = (char*)LDS + w * 2304;
#pragma unroll
        for (int i = 0; i < 4; i++) {
            const long long gm = m0 + wr * 64 + i * 16 + erow;
#pragma unroll
            for (int jc = 0; jc < NJ / 2; jc++) {
#pragma unroll
                for (int jj = 0; jj < 2; jj++)
#pragma unroll
                    for (int r = 0; r < 4; r++)
                        *(float*)(eb + (quad * 4 + r) * 144 + (jj * 16 + lrow) * 4) =
                            acc[i][2 * jc + jj][r] * scale;
#pragma unroll
                for (int c = 0; c < 2; c++) {
                    f32x4 d = *(f32x4*)(eb + erow * 144 + ep * 32 + c * 16);
                    *(f32x4*)((float*)C + gm * ldc + (n0 + wc * (TN / 2) + jc * 32 + ep * 8 + c * 4)) = d;
                }
            }
        }
    }
}

// ---------- fused prep: x fp32->bf16 cast  +  W_{q,k,v} transpose-cast ----------
__global__ __launch_bounds__(256) void prep_fused(
    const float4* __restrict__ xin, unsigned short* __restrict__ xout, int n4, int nCast,
    const float* __restrict__ W0, const float* __restrict__ W1,
    const float* __restrict__ W2, unsigned short* __restrict__ wout, int n)
{
    const int tid = threadIdx.x;
    if ((int)blockIdx.x < nCast) {
        int i = blockIdx.x * 256 + tid;
        if (i >= n4) return;
        float4 v = xin[i];
        union { unsigned short u[4]; uint2 p; } o;
        o.u[0] = f2bf(v.x); o.u[1] = f2bf(v.y); o.u[2] = f2bf(v.z); o.u[3] = f2bf(v.w);
        *(uint2*)(xout + (long long)i * 4) = o.p;
        return;
    }
    const int bx = blockIdx.x - nCast;       // 0..3071
    const int wz = bx >> 10, rem = bx & 1023;
    const int wy = rem >> 5, wx = rem & 31;
    const float* in = (wz == 0) ? W0 : (wz == 1) ? W1 : W2;
    unsigned short* out = wout + (long long)wz * n * n;
    __shared__ float tile[32][33];
    const int tx = tid & 31, ty = tid >> 5;
    const int c0 = wx * 32, r0 = wy * 32;
#pragma unroll
    for (int i = 0; i < 4; i++)
        tile[ty + i * 8][tx] = in[(long long)(r0 + ty + i * 8) * n + c0 + tx];
    __syncthreads();
#pragma unroll
    for (int i = 0; i < 4; i++)
        out[(long long)(c0 + ty + i * 8) * n + r0 + tx] = f2bf(tile[tx][ty + i * 8]);
}

// ---------- causal softmax: S (bf16, B*T rows of T) -> P (bf16), vectorized ----------
__global__ __launch_bounds__(256) void causal_softmax_bf16(
    const unsigned short* __restrict__ S, unsigned short* __restrict__ P, int T)
{
    const int row = blockIdx.x;            // 0 .. B*T-1
    const int t   = row & (T - 1);
    const int L   = t + 1;
    const unsigned short* s = S + (long long)row * T;
    unsigned short* p = P + (long long)row * T;
    const int tid  = threadIdx.x;
    const int base = tid * 8;

    uint4 raw = *(const uint4*)(s + base);
    unsigned rr[4] = {raw.x, raw.y, raw.z, raw.w};
    float v[8];
#pragma unroll
    for (int k = 0; k < 4; k++) {
        union { unsigned u; float f; } a, b;
        a.u = (rr[k] & 0xFFFFu) << 16;
        b.u = rr[k] & 0xFFFF0000u;
        v[2 * k] = a.f; v[2 * k + 1] = b.f;
    }
    float mx = -3.0e38f;
#pragma unroll
    for (int k = 0; k < 8; k++) {
        if (base + k >= L) v[k] = -3.0e38f;
        mx = fmaxf(mx, v[k]);
    }
#pragma unroll
    for (int off = 32; off; off >>= 1) mx = fmaxf(mx, __shfl_xor(mx, off));
    __shared__ float red[4], red2[4];
    const int wid = tid >> 6, lid = tid & 63;
    if (lid == 0) red[wid] = mx;
    __syncthreads();
    mx = fmaxf(fmaxf(red[0], red[1]), fmaxf(red[2], red[3]));

    float sum = 0.f;
#pragma unroll
    for (int k = 0; k < 8; k++) { v[k] = __expf(v[k] - mx); sum += v[k]; }
#pragma unroll
    for (int off = 32; off; off >>= 1) sum += __shfl_xor(sum, off);
    if (lid == 0) red2[wid] = sum;
    __syncthreads();
    sum = red2[0] + red2[1] + red2[2] + red2[3];
    const float inv = 1.0f / sum;

    union { unsigned short u[8]; uint4 q; } o;
#pragma unroll
    for (int k = 0; k < 8; k++) o.u[k] = f2bf(v[k] * inv);
    *(uint4*)(p + base) = o.q;
}

// ---------- launch ----------
extern "C" void kernel_launch(void* const* d_in, const int* in_sizes, int n_in,
                              void* d_out, int out_size, void* d_ws, size_t ws_size,
                              hipStream_t stream)
{
    const int B = 4, T = 2048, C = 1024, D = 1024;
    const float* x  = (const float*)d_in[0];
    const float* Wq = (const float*)d_in[1];
    const float* Wk = (const float*)d_in[2];
    const float* Wv = (const float*)d_in[3];
    float* out = (float*)d_out;
    char* ws = (char*)d_ws;

    const size_t MB = 1ull << 20;
    unsigned short* Xbf   = (unsigned short*)(ws + 0);
    unsigned short* WqkvT = (unsigned short*)(ws + 16 * MB);
    unsigned short* QK    = (unsigned short*)(ws + 22 * MB);
    unsigned short* Vt    = (unsigned short*)(ws + 54 * MB);
    unsigned short* Sbf   = (unsigned short*)(ws + 70 * MB);
    unsigned short* P     = (unsigned short*)(ws + 0);

    const long long sX  = (long long)T * C;        // 2048*1024
    const long long sQK = (long long)T * 2 * D;    // 2048*2048
    const long long sVt = (long long)D * T;        // 1024*2048
    const long long sS  = (long long)T * T;        // 2048*2048
    const long long sO  = (long long)T * D;        // 2048*1024

    // 1) fused prep: x -> bf16 cast  +  W^T cast (one launch)
    {
        int n4 = B * T * C / 4;                    // 2,097,152
        int nCast = (n4 + 255) / 256;              // 8192
        prep_fused<<<dim3(nCast + 3072), dim3(256), 0, stream>>>(
            (const float4*)x, Xbf, n4, nCast, Wq, Wk, Wv, WqkvT, 1024);
    }
    // 2) fused QKV GEMM (128x256 tile): Q,K -> QK; V -> Vt transposed (VFOLD)
    {
        dim3 g(192, 1, 4), b(256);
        gemm_bt<unsigned short, false, true, 1, 256><<<g, b, 0, stream>>>(
            Xbf, WqkvT, QK, Vt, 2048, 3072, 1024, 1024, 1024, 2048,
            /*ldvt*/ T, /*nsplit*/ 2048, sX, 0, sQK, sVt, 1.0f);
    }
    // 3) S = Q K^T / 32 -> bf16 (128x128 tile), triangular causal grid, z-pure XCD
    {
        dim3 g(136, 1, 4), b(256);
        gemm_bt<unsigned short, false, false, 2, 128><<<g, b, 0, stream>>>(
            QK, QK + D, Sbf, nullptr, 2048, 2048, 1024, 2 * D, 2 * D, 2048,
            0, 0, sQK, sQK, sS, 0, 0.03125f);
    }
    // 4) causal softmax (bf16 -> bf16)
    {
        causal_softmax_bf16<<<dim3(B * T), dim3(256), 0, stream>>>(Sbf, P, T);
    }
    // 5) O = P V (128x128 tile, K clamped causally, heavy-first), z-pure XCD
    {
        dim3 g(128, 1, 4), b(256);
        gemm_bt<float, true, false, 3, 128><<<g, b, 0, stream>>>(
            P, Vt, out, nullptr, 2048, 1024, 2048, 2048, 2048, 1024,
            0, 0, sS, sVt, sO, 0, 1.0f);
    }
    (void)in_sizes; (void)n_in; (void)out_size; (void)ws_size;
}